// Round 23
// baseline (751.132 us; speedup 1.0000x reference)
//
#include <hip/hip_runtime.h>
#include <hip/hip_bf16.h>
#include <math.h>

// build o23 = n22 + tail minwaves 4 + zchain fusion (irfftz+mix+rfftz) +
// LDS twiddle tables in the small FFT kernels.
#define XYZ 135168   // 64*64*33
#define W 20
#define NMODE 2048   // 16*16*8
#define NREAL 3584   // 16*16*14

__device__ __forceinline__ float o23_erf(float x) {
    float s = (x < 0.f) ? -1.f : 1.f;
    float a = fabsf(x);
    float t = 1.f / fmaf(0.3275911f, a, 1.f);
    float poly = t * fmaf(t, fmaf(t, fmaf(t, fmaf(t, 1.061405429f, -1.453152027f),
                                           1.421413741f), -0.284496736f), 0.254829592f);
    float e = __expf(-a * a);
    return s * (1.f - poly * e);
}
__device__ __forceinline__ float o23_gelu(float v) {
    return 0.5f * v * (1.0f + o23_erf(v * 0.7071067811865476f));
}

__global__ __launch_bounds__(256, 4)
void o23_fc0(const float* __restrict__ xr_in, const float* __restrict__ xi_in,
             const float* __restrict__ fr, const float* __restrict__ fi,
             float* __restrict__ xre, float* __restrict__ xim) {
    int idx = blockIdx.x * blockDim.x + threadIdx.x;
    if (idx >= 4 * XYZ) return;
    int b = idx / XYZ, p = idx % XYZ;
    float ar[3], ai[3];
#pragma unroll
    for (int i = 0; i < 3; i++) {
        ar[i] = xr_in[(size_t)(b * 3 + i) * XYZ + p];
        ai[i] = xi_in[(size_t)(b * 3 + i) * XYZ + p];
    }
#pragma unroll
    for (int o = 0; o < W; o++) {
        float rr = 0.f, ii = 0.f;
#pragma unroll
        for (int i = 0; i < 3; i++) {
            float wr = fr[i * W + o], wi = fi[i * W + o];
            rr += ar[i] * wr - ai[i] * wi;
            ii += ar[i] * wi + ai[i] * wr;
        }
        xre[(size_t)(b * W + o) * XYZ + p] = rr;
        xim[(size_t)(b * W + o) * XYZ + p] = ii;
    }
}

// FUSED gather + ifftX + ifftY per (bc, kz) plane, LDS twiddle table.
__global__ __launch_bounds__(256, 4)
void o23_ixy(const float* __restrict__ xre, const float* __restrict__ xim,
             float* __restrict__ aRe, float* __restrict__ aIm) {
    __shared__ float s0r[256], s0i[256], s1r[256], s1i[256];
    __shared__ float twc[16], tws[16];
    int bc = blockIdx.x >> 3;
    int kz = blockIdx.x & 7;
    int t = threadIdx.x;
    int hi = t >> 4, lo = t & 15;
    if (t < 16) {
        float s, c;
        sincosf((float)t * 0.39269908169872414f, &s, &c);  // +2*pi*t/16
        twc[t] = c; tws[t] = s;
    }
    {
        int row = (hi < 8) ? hi : hi + 48;
        int col = (lo < 8) ? lo : lo + 48;
        int off = (row * 64 + col) * 33 + kz;
        s0r[t] = xre[(size_t)bc * XYZ + off];
        s0i[t] = xim[(size_t)bc * XYZ + off];
    }
    __syncthreads();
    {   // ifftX
        int nx = hi, ky = lo;
        float accr = 0.f, acci = 0.f;
        for (int kx = 0; kx < 16; kx++) {
            float vr = s0r[kx * 16 + ky], vi = s0i[kx * 16 + ky];
            int m = (kx * nx) & 15;
            float c = twc[m], s = tws[m];
            accr += vr * c - vi * s;
            acci += vr * s + vi * c;
        }
        s1r[t] = accr * 0.0625f;
        s1i[t] = acci * 0.0625f;
    }
    __syncthreads();
    {   // ifftY
        int nx = hi, ny = lo;
        float accr = 0.f, acci = 0.f;
        for (int ky = 0; ky < 16; ky++) {
            float vr = s1r[nx * 16 + ky], vi = s1i[nx * 16 + ky];
            int m = (ky * ny) & 15;
            float c = twc[m], s = tws[m];
            accr += vr * c - vi * s;
            acci += vr * s + vi * c;
        }
        size_t o = (size_t)bc * 2048 + (size_t)t * 8 + kz;
        aRe[o] = accr * 0.0625f;
        aIm[o] = acci * 0.0625f;
    }
}

// FUSED irfftZ -> mix -> rfftZ. One block per (b, 4-q tile): 256 blocks.
// a layout: [bc][q][k], q = nx*16+ny in [0,256), k in [0,8)
__global__ __launch_bounds__(256, 4)
void o23_zchain(const float* __restrict__ aRe, const float* __restrict__ aIm,
                const float* __restrict__ wconv, int l,
                float* __restrict__ tRe, float* __restrict__ tIm) {
    __shared__ float sar[640], sai[640];    // [c][dq][k] = c*32 + dq*8 + k
    __shared__ float sr1[1120], sr2[1120];  // [c][dq][nz] = c*56 + dq*14 + nz
    __shared__ float twc[14], tws[14];
    int b = blockIdx.x >> 6;
    int q0 = (blockIdx.x & 63) * 4;
    int tid = threadIdx.x;
    if (tid < 14) {
        float s, c;
        sincosf((float)tid * 0.4487989505128276f, &s, &c);  // 2*pi*tid/14
        twc[tid] = c; tws[tid] = s;
    }
    for (int t = tid; t < 640; t += 256) {
        int c = t >> 5;
        int dq = (t >> 3) & 3;
        int k = t & 7;
        size_t g = (size_t)(b * 20 + c) * 2048 + (size_t)(q0 + dq) * 8 + k;
        sar[t] = aRe[g];
        sai[t] = aIm[g];
    }
    __syncthreads();
    // irfftZ (Im of DC & Nyquist ignored, matches pocketfft c2r)
    for (int t = tid; t < 1120; t += 256) {
        int c = t / 56;
        int rem = t % 56;
        int dq = rem / 14, nz = rem % 14;
        int base = c * 32 + dq * 8;
        float acc = sar[base];
        float re7 = sar[base + 7];
        acc += (nz & 1) ? -re7 : re7;
        for (int k = 1; k < 7; k++) {
            int m = (k * nz) % 14;
            acc += 2.f * (sar[base + k] * twc[m] - sai[base + k] * tws[m]);
        }
        sr1[t] = acc * (1.0f / 14.0f);
    }
    __syncthreads();
    // mix: sr2[o][rem] = sum_i sr1[i][rem] * wl[(i*20+o)*3584 + p]
    {
        const float* wl = wconv + (size_t)l * W * W * NREAL;
        for (int t = tid; t < 1120; t += 256) {
            int o = t / 56;
            int rem = t % 56;
            int dq = rem / 14, nz = rem % 14;
            int p = (q0 + dq) * 14 + nz;
            float acc = 0.f;
#pragma unroll 4
            for (int i = 0; i < W; i++)
                acc += sr1[i * 56 + rem] * wl[(size_t)(i * W + o) * NREAL + p];
            sr2[t] = acc;
        }
    }
    __syncthreads();
    // rfftZ
    for (int t = tid; t < 640; t += 256) {
        int c = t >> 5;
        int dq = (t >> 3) & 3;
        int k = t & 7;
        int base = c * 56 + dq * 14;
        float accr = 0.f, acci = 0.f;
        for (int n = 0; n < 14; n++) {
            float v = sr2[base + n];
            int m = (k * n) % 14;
            accr += v * twc[m];
            acci -= v * tws[m];
        }
        size_t g = (size_t)(b * 20 + c) * 2048 + (size_t)(q0 + dq) * 8 + k;
        tRe[g] = accr;
        tIm[g] = acci;
    }
}

// FUSED fftX + fftY per (bc, kz) plane.
__global__ __launch_bounds__(256, 4)
void o23_fxy(const float* __restrict__ c1Re, const float* __restrict__ c1Im,
             float* __restrict__ eRe, float* __restrict__ eIm) {
    __shared__ float s0r[256], s0i[256], s1r[256], s1i[256];
    __shared__ float twc[16], tws[16];
    int bc = blockIdx.x >> 3;
    int kz = blockIdx.x & 7;
    int t = threadIdx.x;
    int hi = t >> 4, lo = t & 15;
    if (t < 16) {
        float s, c;
        sincosf((float)t * 0.39269908169872414f, &s, &c);
        twc[t] = c; tws[t] = s;
    }
    {
        size_t o = (size_t)bc * 2048 + (size_t)t * 8 + kz;
        s0r[t] = c1Re[o];
        s0i[t] = c1Im[o];
    }
    __syncthreads();
    {   // fftX (e^{-i})
        int kx = hi, ny = lo;
        float accr = 0.f, acci = 0.f;
        for (int nx = 0; nx < 16; nx++) {
            float vr = s0r[nx * 16 + ny], vi = s0i[nx * 16 + ny];
            int m = (kx * nx) & 15;
            float c = twc[m], s = tws[m];
            accr += vr * c + vi * s;
            acci += vi * c - vr * s;
        }
        s1r[t] = accr;
        s1i[t] = acci;
    }
    __syncthreads();
    {   // fftY
        int kx = hi, ky = lo;
        float accr = 0.f, acci = 0.f;
        for (int ny = 0; ny < 16; ny++) {
            float vr = s1r[kx * 16 + ny], vi = s1i[kx * 16 + ny];
            int m = (ky * ny) & 15;
            float c = twc[m], s = tws[m];
            accr += vr * c + vi * s;
            acci += vi * c - vr * s;
        }
        size_t o = (size_t)bc * 2048 + (size_t)t * 8 + kz;
        eRe[o] = accr;
        eIm[o] = acci;
    }
}

__global__ __launch_bounds__(256, 4)
void o23_combine(float* __restrict__ xre, float* __restrict__ xim,
                 const float* __restrict__ ere, const float* __restrict__ eim,
                 const float* __restrict__ wpt_r, const float* __restrict__ wpt_i,
                 int l, const float* __restrict__ smooth) {
    __shared__ float wr[W * W], wi[W * W];
    for (int i = threadIdx.x; i < W * W; i += blockDim.x) {
        wr[i] = wpt_r[l * W * W + i];
        wi[i] = wpt_i[l * W * W + i];
    }
    __syncthreads();
    int idx = blockIdx.x * blockDim.x + threadIdx.x;
    if (idx >= 4 * XYZ) return;
    int b = idx / XYZ, p = idx % XYZ;
    int gz = p % 33;
    int gxy = p / 33;
    int gy = gxy & 63;
    int gx = gxy >> 6;
    int kx = (gx < 8) ? gx : ((gx >= 56) ? gx - 48 : -1);
    int ky = (gy < 8) ? gy : ((gy >= 56) ? gy - 48 : -1);
    bool corner = (kx >= 0) && (ky >= 0) && (gz < 8);
    float sm = smooth[p];
    float ar[W], ai[W];
#pragma unroll
    for (int i = 0; i < W; i++) {
        ar[i] = xre[(size_t)(b * W + i) * XYZ + p];
        ai[i] = xim[(size_t)(b * W + i) * XYZ + p];
    }
    int ebase = corner ? (b * W * NMODE + (kx * 16 + ky) * 8 + gz) : 0;
    for (int o = 0; o < W; o++) {
        float rr = 0.f, ii = 0.f;
#pragma unroll
        for (int i = 0; i < W; i++) {
            float wwr = wr[i * W + o], wwi = wi[i * W + o];
            rr += ar[i] * wwr - ai[i] * wwi;
            ii += ar[i] * wwi + ai[i] * wwr;
        }
        if (corner) {
            rr += ere[ebase + o * NMODE];
            ii += eim[ebase + o * NMODE];
        }
        rr *= sm;
        ii *= sm;
        rr = o23_gelu(rr);
        ii = o23_gelu(ii);
        xre[(size_t)(b * W + o) * XYZ + p] = rr;
        xim[(size_t)(b * W + o) * XYZ + p] = ii;
    }
}

// TAIL: fused combine l=3 (no gelu) + fc1 -> cgelu -> fc2 (real out).
// minwaves 4: LDS 27.1 KB x4 = 108 KB <= 160 KB, VGPR cap 128.
__global__ __launch_bounds__(256, 4)
void o23_tail(const float* __restrict__ xre, const float* __restrict__ xim,
              const float* __restrict__ ere, const float* __restrict__ eim,
              const float* __restrict__ wpt_r, const float* __restrict__ wpt_i,
              const float* __restrict__ smooth,
              const float* __restrict__ f1r, const float* __restrict__ f1i,
              const float* __restrict__ f2r, const float* __restrict__ f2i,
              float* __restrict__ outf) {
    __shared__ __align__(16) float w1r[W * 128], w1i[W * 128];
    __shared__ __align__(16) float w2r[3 * 128], w2i[3 * 128];
    __shared__ float pwr[W * W], pwi[W * W];
    for (int i = threadIdx.x; i < W * 128; i += blockDim.x) {
        w1r[i] = f1r[i];
        w1i[i] = f1i[i];
    }
    for (int i = threadIdx.x; i < 3 * 128; i += blockDim.x) {
        int j = i & 127, o = i >> 7;
        w2r[o * 128 + j] = f2r[j * 3 + o];
        w2i[o * 128 + j] = f2i[j * 3 + o];
    }
    for (int i = threadIdx.x; i < W * W; i += blockDim.x) {
        pwr[i] = wpt_r[3 * W * W + i];
        pwi[i] = wpt_i[3 * W * W + i];
    }
    __syncthreads();
    int idx = blockIdx.x * blockDim.x + threadIdx.x;
    if (idx >= 4 * XYZ) return;
    int b = idx / XYZ, p = idx % XYZ;
    int gz = p % 33;
    int gxy = p / 33;
    int gy = gxy & 63;
    int gx = gxy >> 6;
    int kxc = (gx < 8) ? gx : ((gx >= 56) ? gx - 48 : -1);
    int kyc = (gy < 8) ? gy : ((gy >= 56) ? gy - 48 : -1);
    bool corner = (kxc >= 0) && (kyc >= 0) && (gz < 8);
    float sm = smooth[p];
    float rr_[W], ri_[W];
    {
        float ar[W], ai[W];
#pragma unroll
        for (int i = 0; i < W; i++) {
            ar[i] = xre[(size_t)(b * W + i) * XYZ + p];
            ai[i] = xim[(size_t)(b * W + i) * XYZ + p];
        }
        int ebase = corner ? (b * W * NMODE + (kxc * 16 + kyc) * 8 + gz) : 0;
#pragma unroll 1
        for (int o = 0; o < W; o++) {
            float rr = 0.f, ii = 0.f;
#pragma unroll
            for (int i = 0; i < W; i++) {
                float wwr = pwr[i * W + o], wwi = pwi[i * W + o];
                rr += ar[i] * wwr - ai[i] * wwi;
                ii += ar[i] * wwi + ai[i] * wwr;
            }
            if (corner) {
                rr += ere[ebase + o * NMODE];
                ii += eim[ebase + o * NMODE];
            }
            rr_[o] = rr * sm;
            ri_[o] = ii * sm;
        }
    }
    float accr[3] = {0.f, 0.f, 0.f};
    for (int jc = 0; jc < 16; jc++) {
        int jb = jc * 8;
        float tr[8], ti[8];
#pragma unroll
        for (int jj = 0; jj < 8; jj++) { tr[jj] = 0.f; ti[jj] = 0.f; }
#pragma unroll 1
        for (int i = 0; i < W; i++) {
            float4 wrA = *(const float4*)&w1r[i * 128 + jb];
            float4 wrB = *(const float4*)&w1r[i * 128 + jb + 4];
            float4 wiA = *(const float4*)&w1i[i * 128 + jb];
            float4 wiB = *(const float4*)&w1i[i * 128 + jb + 4];
            float xr_ = rr_[i], xi_ = ri_[i];
            tr[0] += xr_ * wrA.x - xi_ * wiA.x;  ti[0] += xr_ * wiA.x + xi_ * wrA.x;
            tr[1] += xr_ * wrA.y - xi_ * wiA.y;  ti[1] += xr_ * wiA.y + xi_ * wrA.y;
            tr[2] += xr_ * wrA.z - xi_ * wiA.z;  ti[2] += xr_ * wiA.z + xi_ * wrA.z;
            tr[3] += xr_ * wrA.w - xi_ * wiA.w;  ti[3] += xr_ * wiA.w + xi_ * wrA.w;
            tr[4] += xr_ * wrB.x - xi_ * wiB.x;  ti[4] += xr_ * wiB.x + xi_ * wrB.x;
            tr[5] += xr_ * wrB.y - xi_ * wiB.y;  ti[5] += xr_ * wiB.y + xi_ * wrB.y;
            tr[6] += xr_ * wrB.z - xi_ * wiB.z;  ti[6] += xr_ * wiB.z + xi_ * wrB.z;
            tr[7] += xr_ * wrB.w - xi_ * wiB.w;  ti[7] += xr_ * wiB.w + xi_ * wrB.w;
        }
#pragma unroll
        for (int jj = 0; jj < 8; jj++) {
            tr[jj] = o23_gelu(tr[jj]);
            ti[jj] = o23_gelu(ti[jj]);
        }
#pragma unroll
        for (int o = 0; o < 3; o++) {
            float4 crA = *(const float4*)&w2r[o * 128 + jb];
            float4 crB = *(const float4*)&w2r[o * 128 + jb + 4];
            float4 ciA = *(const float4*)&w2i[o * 128 + jb];
            float4 ciB = *(const float4*)&w2i[o * 128 + jb + 4];
            accr[o] += tr[0] * crA.x - ti[0] * ciA.x;
            accr[o] += tr[1] * crA.y - ti[1] * ciA.y;
            accr[o] += tr[2] * crA.z - ti[2] * ciA.z;
            accr[o] += tr[3] * crA.w - ti[3] * ciA.w;
            accr[o] += tr[4] * crB.x - ti[4] * ciB.x;
            accr[o] += tr[5] * crB.y - ti[5] * ciB.y;
            accr[o] += tr[6] * crB.z - ti[6] * ciB.z;
            accr[o] += tr[7] * crB.w - ti[7] * ciB.w;
        }
    }
#pragma unroll
    for (int o = 0; o < 3; o++) {
        size_t k = (size_t)(b * 3 + o) * XYZ + p;
        outf[k] = __bfloat162float(__float2bfloat16(accr[o]));
    }
}

extern "C" void kernel_launch(void* const* d_in, const int* in_sizes, int n_in,
                              void* d_out, int out_size, void* d_ws, size_t ws_size,
                              hipStream_t stream) {
    const float* x_r    = (const float*)d_in[0];
    const float* x_i    = (const float*)d_in[1];
    const float* smooth = (const float*)d_in[2];
    const float* wconv  = (const float*)d_in[3];
    const float* wpt_r  = (const float*)d_in[4];
    const float* wpt_i  = (const float*)d_in[5];
    const float* fc0_r  = (const float*)d_in[6];
    const float* fc0_i  = (const float*)d_in[7];
    const float* fc1_r  = (const float*)d_in[8];
    const float* fc1_i  = (const float*)d_in[9];
    const float* fc2_r  = (const float*)d_in[10];
    const float* fc2_i  = (const float*)d_in[11];
    float* outf = (float*)d_out;

    const size_t NBW = (size_t)4 * W * XYZ;
    const size_t NM  = (size_t)80 * NMODE;

    float* ws  = (float*)d_ws;
    float* eRe = ws;
    float* eIm = eRe + NM;
    float* tRe = eIm + NM;
    float* tIm = tRe + NM;
    float* xre = tIm + NM;
    float* xim = xre + NBW;

    dim3 blk(256);
    const int gP = (4 * XYZ) / 256;    // 2112

    o23_fc0<<<gP, blk, 0, stream>>>(x_r, x_i, fc0_r, fc0_i, xre, xim);
    for (int l = 0; l < 4; l++) {
        o23_ixy<<<640, blk, 0, stream>>>(xre, xim, tRe, tIm);
        o23_zchain<<<256, blk, 0, stream>>>(tRe, tIm, wconv, l, eRe, eIm);
        o23_fxy<<<640, blk, 0, stream>>>(eRe, eIm, tRe, tIm);
        if (l < 3)
            o23_combine<<<gP, blk, 0, stream>>>(xre, xim, tRe, tIm,
                                                wpt_r, wpt_i, l, smooth);
    }
    o23_tail<<<gP, blk, 0, stream>>>(xre, xim, tRe, tIm, wpt_r, wpt_i, smooth,
                                     fc1_r, fc1_i, fc2_r, fc2_i, outf);
}

// Round 24
// 687.833 us; speedup vs baseline: 1.0920x; 1.0920x over previous
//
#include <hip/hip_runtime.h>
#include <hip/hip_bf16.h>
#include <math.h>

// build p24 = o23 (zchain fusion + twiddle tables kept) with the tail reverted
// to minwaves 2 (o23's minwaves-4 capped VGPR at 64 -> spills returned).
#define XYZ 135168   // 64*64*33
#define W 20
#define NMODE 2048   // 16*16*8
#define NREAL 3584   // 16*16*14

__device__ __forceinline__ float p24_erf(float x) {
    float s = (x < 0.f) ? -1.f : 1.f;
    float a = fabsf(x);
    float t = 1.f / fmaf(0.3275911f, a, 1.f);
    float poly = t * fmaf(t, fmaf(t, fmaf(t, fmaf(t, 1.061405429f, -1.453152027f),
                                           1.421413741f), -0.284496736f), 0.254829592f);
    float e = __expf(-a * a);
    return s * (1.f - poly * e);
}
__device__ __forceinline__ float p24_gelu(float v) {
    return 0.5f * v * (1.0f + p24_erf(v * 0.7071067811865476f));
}

__global__ __launch_bounds__(256, 4)
void p24_fc0(const float* __restrict__ xr_in, const float* __restrict__ xi_in,
             const float* __restrict__ fr, const float* __restrict__ fi,
             float* __restrict__ xre, float* __restrict__ xim) {
    int idx = blockIdx.x * blockDim.x + threadIdx.x;
    if (idx >= 4 * XYZ) return;
    int b = idx / XYZ, p = idx % XYZ;
    float ar[3], ai[3];
#pragma unroll
    for (int i = 0; i < 3; i++) {
        ar[i] = xr_in[(size_t)(b * 3 + i) * XYZ + p];
        ai[i] = xi_in[(size_t)(b * 3 + i) * XYZ + p];
    }
#pragma unroll
    for (int o = 0; o < W; o++) {
        float rr = 0.f, ii = 0.f;
#pragma unroll
        for (int i = 0; i < 3; i++) {
            float wr = fr[i * W + o], wi = fi[i * W + o];
            rr += ar[i] * wr - ai[i] * wi;
            ii += ar[i] * wi + ai[i] * wr;
        }
        xre[(size_t)(b * W + o) * XYZ + p] = rr;
        xim[(size_t)(b * W + o) * XYZ + p] = ii;
    }
}

__global__ __launch_bounds__(256, 4)
void p24_ixy(const float* __restrict__ xre, const float* __restrict__ xim,
             float* __restrict__ aRe, float* __restrict__ aIm) {
    __shared__ float s0r[256], s0i[256], s1r[256], s1i[256];
    __shared__ float twc[16], tws[16];
    int bc = blockIdx.x >> 3;
    int kz = blockIdx.x & 7;
    int t = threadIdx.x;
    int hi = t >> 4, lo = t & 15;
    if (t < 16) {
        float s, c;
        sincosf((float)t * 0.39269908169872414f, &s, &c);
        twc[t] = c; tws[t] = s;
    }
    {
        int row = (hi < 8) ? hi : hi + 48;
        int col = (lo < 8) ? lo : lo + 48;
        int off = (row * 64 + col) * 33 + kz;
        s0r[t] = xre[(size_t)bc * XYZ + off];
        s0i[t] = xim[(size_t)bc * XYZ + off];
    }
    __syncthreads();
    {
        int nx = hi, ky = lo;
        float accr = 0.f, acci = 0.f;
        for (int kx = 0; kx < 16; kx++) {
            float vr = s0r[kx * 16 + ky], vi = s0i[kx * 16 + ky];
            int m = (kx * nx) & 15;
            float c = twc[m], s = tws[m];
            accr += vr * c - vi * s;
            acci += vr * s + vi * c;
        }
        s1r[t] = accr * 0.0625f;
        s1i[t] = acci * 0.0625f;
    }
    __syncthreads();
    {
        int nx = hi, ny = lo;
        float accr = 0.f, acci = 0.f;
        for (int ky = 0; ky < 16; ky++) {
            float vr = s1r[nx * 16 + ky], vi = s1i[nx * 16 + ky];
            int m = (ky * ny) & 15;
            float c = twc[m], s = tws[m];
            accr += vr * c - vi * s;
            acci += vr * s + vi * c;
        }
        size_t o = (size_t)bc * 2048 + (size_t)t * 8 + kz;
        aRe[o] = accr * 0.0625f;
        aIm[o] = acci * 0.0625f;
    }
}

__global__ __launch_bounds__(256, 4)
void p24_zchain(const float* __restrict__ aRe, const float* __restrict__ aIm,
                const float* __restrict__ wconv, int l,
                float* __restrict__ tRe, float* __restrict__ tIm) {
    __shared__ float sar[640], sai[640];
    __shared__ float sr1[1120], sr2[1120];
    __shared__ float twc[14], tws[14];
    int b = blockIdx.x >> 6;
    int q0 = (blockIdx.x & 63) * 4;
    int tid = threadIdx.x;
    if (tid < 14) {
        float s, c;
        sincosf((float)tid * 0.4487989505128276f, &s, &c);
        twc[tid] = c; tws[tid] = s;
    }
    for (int t = tid; t < 640; t += 256) {
        int c = t >> 5;
        int dq = (t >> 3) & 3;
        int k = t & 7;
        size_t g = (size_t)(b * 20 + c) * 2048 + (size_t)(q0 + dq) * 8 + k;
        sar[t] = aRe[g];
        sai[t] = aIm[g];
    }
    __syncthreads();
    for (int t = tid; t < 1120; t += 256) {
        int c = t / 56;
        int rem = t % 56;
        int dq = rem / 14, nz = rem % 14;
        int base = c * 32 + dq * 8;
        float acc = sar[base];
        float re7 = sar[base + 7];
        acc += (nz & 1) ? -re7 : re7;
        for (int k = 1; k < 7; k++) {
            int m = (k * nz) % 14;
            acc += 2.f * (sar[base + k] * twc[m] - sai[base + k] * tws[m]);
        }
        sr1[t] = acc * (1.0f / 14.0f);
    }
    __syncthreads();
    {
        const float* wl = wconv + (size_t)l * W * W * NREAL;
        for (int t = tid; t < 1120; t += 256) {
            int o = t / 56;
            int rem = t % 56;
            int dq = rem / 14, nz = rem % 14;
            int p = (q0 + dq) * 14 + nz;
            float acc = 0.f;
#pragma unroll 4
            for (int i = 0; i < W; i++)
                acc += sr1[i * 56 + rem] * wl[(size_t)(i * W + o) * NREAL + p];
            sr2[t] = acc;
        }
    }
    __syncthreads();
    for (int t = tid; t < 640; t += 256) {
        int c = t >> 5;
        int dq = (t >> 3) & 3;
        int k = t & 7;
        int base = c * 56 + dq * 14;
        float accr = 0.f, acci = 0.f;
        for (int n = 0; n < 14; n++) {
            float v = sr2[base + n];
            int m = (k * n) % 14;
            accr += v * twc[m];
            acci -= v * tws[m];
        }
        size_t g = (size_t)(b * 20 + c) * 2048 + (size_t)(q0 + dq) * 8 + k;
        tRe[g] = accr;
        tIm[g] = acci;
    }
}

__global__ __launch_bounds__(256, 4)
void p24_fxy(const float* __restrict__ c1Re, const float* __restrict__ c1Im,
             float* __restrict__ eRe, float* __restrict__ eIm) {
    __shared__ float s0r[256], s0i[256], s1r[256], s1i[256];
    __shared__ float twc[16], tws[16];
    int bc = blockIdx.x >> 3;
    int kz = blockIdx.x & 7;
    int t = threadIdx.x;
    int hi = t >> 4, lo = t & 15;
    if (t < 16) {
        float s, c;
        sincosf((float)t * 0.39269908169872414f, &s, &c);
        twc[t] = c; tws[t] = s;
    }
    {
        size_t o = (size_t)bc * 2048 + (size_t)t * 8 + kz;
        s0r[t] = c1Re[o];
        s0i[t] = c1Im[o];
    }
    __syncthreads();
    {
        int kx = hi, ny = lo;
        float accr = 0.f, acci = 0.f;
        for (int nx = 0; nx < 16; nx++) {
            float vr = s0r[nx * 16 + ny], vi = s0i[nx * 16 + ny];
            int m = (kx * nx) & 15;
            float c = twc[m], s = tws[m];
            accr += vr * c + vi * s;
            acci += vi * c - vr * s;
        }
        s1r[t] = accr;
        s1i[t] = acci;
    }
    __syncthreads();
    {
        int kx = hi, ky = lo;
        float accr = 0.f, acci = 0.f;
        for (int ny = 0; ny < 16; ny++) {
            float vr = s1r[kx * 16 + ny], vi = s1i[kx * 16 + ny];
            int m = (ky * ny) & 15;
            float c = twc[m], s = tws[m];
            accr += vr * c + vi * s;
            acci += vi * c - vr * s;
        }
        size_t o = (size_t)bc * 2048 + (size_t)t * 8 + kz;
        eRe[o] = accr;
        eIm[o] = acci;
    }
}

__global__ __launch_bounds__(256, 4)
void p24_combine(float* __restrict__ xre, float* __restrict__ xim,
                 const float* __restrict__ ere, const float* __restrict__ eim,
                 const float* __restrict__ wpt_r, const float* __restrict__ wpt_i,
                 int l, const float* __restrict__ smooth) {
    __shared__ float wr[W * W], wi[W * W];
    for (int i = threadIdx.x; i < W * W; i += blockDim.x) {
        wr[i] = wpt_r[l * W * W + i];
        wi[i] = wpt_i[l * W * W + i];
    }
    __syncthreads();
    int idx = blockIdx.x * blockDim.x + threadIdx.x;
    if (idx >= 4 * XYZ) return;
    int b = idx / XYZ, p = idx % XYZ;
    int gz = p % 33;
    int gxy = p / 33;
    int gy = gxy & 63;
    int gx = gxy >> 6;
    int kx = (gx < 8) ? gx : ((gx >= 56) ? gx - 48 : -1);
    int ky = (gy < 8) ? gy : ((gy >= 56) ? gy - 48 : -1);
    bool corner = (kx >= 0) && (ky >= 0) && (gz < 8);
    float sm = smooth[p];
    float ar[W], ai[W];
#pragma unroll
    for (int i = 0; i < W; i++) {
        ar[i] = xre[(size_t)(b * W + i) * XYZ + p];
        ai[i] = xim[(size_t)(b * W + i) * XYZ + p];
    }
    int ebase = corner ? (b * W * NMODE + (kx * 16 + ky) * 8 + gz) : 0;
    for (int o = 0; o < W; o++) {
        float rr = 0.f, ii = 0.f;
#pragma unroll
        for (int i = 0; i < W; i++) {
            float wwr = wr[i * W + o], wwi = wi[i * W + o];
            rr += ar[i] * wwr - ai[i] * wwi;
            ii += ar[i] * wwi + ai[i] * wwr;
        }
        if (corner) {
            rr += ere[ebase + o * NMODE];
            ii += eim[ebase + o * NMODE];
        }
        rr *= sm;
        ii *= sm;
        rr = p24_gelu(rr);
        ii = p24_gelu(ii);
        xre[(size_t)(b * W + o) * XYZ + p] = rr;
        xim[(size_t)(b * W + o) * XYZ + p] = ii;
    }
}

// TAIL (minwaves 2, VGPR headroom -> no spill): fused combine l=3 (no gelu)
// + fc1 -> cgelu -> fc2 (real out).
__global__ __launch_bounds__(256, 2)
void p24_tail(const float* __restrict__ xre, const float* __restrict__ xim,
              const float* __restrict__ ere, const float* __restrict__ eim,
              const float* __restrict__ wpt_r, const float* __restrict__ wpt_i,
              const float* __restrict__ smooth,
              const float* __restrict__ f1r, const float* __restrict__ f1i,
              const float* __restrict__ f2r, const float* __restrict__ f2i,
              float* __restrict__ outf) {
    __shared__ __align__(16) float w1r[W * 128], w1i[W * 128];
    __shared__ __align__(16) float w2r[3 * 128], w2i[3 * 128];
    __shared__ float pwr[W * W], pwi[W * W];
    for (int i = threadIdx.x; i < W * 128; i += blockDim.x) {
        w1r[i] = f1r[i];
        w1i[i] = f1i[i];
    }
    for (int i = threadIdx.x; i < 3 * 128; i += blockDim.x) {
        int j = i & 127, o = i >> 7;
        w2r[o * 128 + j] = f2r[j * 3 + o];
        w2i[o * 128 + j] = f2i[j * 3 + o];
    }
    for (int i = threadIdx.x; i < W * W; i += blockDim.x) {
        pwr[i] = wpt_r[3 * W * W + i];
        pwi[i] = wpt_i[3 * W * W + i];
    }
    __syncthreads();
    int idx = blockIdx.x * blockDim.x + threadIdx.x;
    if (idx >= 4 * XYZ) return;
    int b = idx / XYZ, p = idx % XYZ;
    int gz = p % 33;
    int gxy = p / 33;
    int gy = gxy & 63;
    int gx = gxy >> 6;
    int kxc = (gx < 8) ? gx : ((gx >= 56) ? gx - 48 : -1);
    int kyc = (gy < 8) ? gy : ((gy >= 56) ? gy - 48 : -1);
    bool corner = (kxc >= 0) && (kyc >= 0) && (gz < 8);
    float sm = smooth[p];
    float rr_[W], ri_[W];
    {
        float ar[W], ai[W];
#pragma unroll
        for (int i = 0; i < W; i++) {
            ar[i] = xre[(size_t)(b * W + i) * XYZ + p];
            ai[i] = xim[(size_t)(b * W + i) * XYZ + p];
        }
        int ebase = corner ? (b * W * NMODE + (kxc * 16 + kyc) * 8 + gz) : 0;
#pragma unroll 1
        for (int o = 0; o < W; o++) {
            float rr = 0.f, ii = 0.f;
#pragma unroll
            for (int i = 0; i < W; i++) {
                float wwr = pwr[i * W + o], wwi = pwi[i * W + o];
                rr += ar[i] * wwr - ai[i] * wwi;
                ii += ar[i] * wwi + ai[i] * wwr;
            }
            if (corner) {
                rr += ere[ebase + o * NMODE];
                ii += eim[ebase + o * NMODE];
            }
            rr_[o] = rr * sm;
            ri_[o] = ii * sm;
        }
    }
    float accr[3] = {0.f, 0.f, 0.f};
    for (int jc = 0; jc < 16; jc++) {
        int jb = jc * 8;
        float tr[8], ti[8];
#pragma unroll
        for (int jj = 0; jj < 8; jj++) { tr[jj] = 0.f; ti[jj] = 0.f; }
#pragma unroll 2
        for (int i = 0; i < W; i++) {
            float4 wrA = *(const float4*)&w1r[i * 128 + jb];
            float4 wrB = *(const float4*)&w1r[i * 128 + jb + 4];
            float4 wiA = *(const float4*)&w1i[i * 128 + jb];
            float4 wiB = *(const float4*)&w1i[i * 128 + jb + 4];
            float xr_ = rr_[i], xi_ = ri_[i];
            tr[0] += xr_ * wrA.x - xi_ * wiA.x;  ti[0] += xr_ * wiA.x + xi_ * wrA.x;
            tr[1] += xr_ * wrA.y - xi_ * wiA.y;  ti[1] += xr_ * wiA.y + xi_ * wrA.y;
            tr[2] += xr_ * wrA.z - xi_ * wiA.z;  ti[2] += xr_ * wiA.z + xi_ * wrA.z;
            tr[3] += xr_ * wrA.w - xi_ * wiA.w;  ti[3] += xr_ * wiA.w + xi_ * wrA.w;
            tr[4] += xr_ * wrB.x - xi_ * wiB.x;  ti[4] += xr_ * wiB.x + xi_ * wrB.x;
            tr[5] += xr_ * wrB.y - xi_ * wiB.y;  ti[5] += xr_ * wiB.y + xi_ * wrB.y;
            tr[6] += xr_ * wrB.z - xi_ * wiB.z;  ti[6] += xr_ * wiB.z + xi_ * wrB.z;
            tr[7] += xr_ * wrB.w - xi_ * wiB.w;  ti[7] += xr_ * wiB.w + xi_ * wrB.w;
        }
#pragma unroll
        for (int jj = 0; jj < 8; jj++) {
            tr[jj] = p24_gelu(tr[jj]);
            ti[jj] = p24_gelu(ti[jj]);
        }
#pragma unroll
        for (int o = 0; o < 3; o++) {
            float4 crA = *(const float4*)&w2r[o * 128 + jb];
            float4 crB = *(const float4*)&w2r[o * 128 + jb + 4];
            float4 ciA = *(const float4*)&w2i[o * 128 + jb];
            float4 ciB = *(const float4*)&w2i[o * 128 + jb + 4];
            accr[o] += tr[0] * crA.x - ti[0] * ciA.x;
            accr[o] += tr[1] * crA.y - ti[1] * ciA.y;
            accr[o] += tr[2] * crA.z - ti[2] * ciA.z;
            accr[o] += tr[3] * crA.w - ti[3] * ciA.w;
            accr[o] += tr[4] * crB.x - ti[4] * ciB.x;
            accr[o] += tr[5] * crB.y - ti[5] * ciB.y;
            accr[o] += tr[6] * crB.z - ti[6] * ciB.z;
            accr[o] += tr[7] * crB.w - ti[7] * ciB.w;
        }
    }
#pragma unroll
    for (int o = 0; o < 3; o++) {
        size_t k = (size_t)(b * 3 + o) * XYZ + p;
        outf[k] = __bfloat162float(__float2bfloat16(accr[o]));
    }
}

extern "C" void kernel_launch(void* const* d_in, const int* in_sizes, int n_in,
                              void* d_out, int out_size, void* d_ws, size_t ws_size,
                              hipStream_t stream) {
    const float* x_r    = (const float*)d_in[0];
    const float* x_i    = (const float*)d_in[1];
    const float* smooth = (const float*)d_in[2];
    const float* wconv  = (const float*)d_in[3];
    const float* wpt_r  = (const float*)d_in[4];
    const float* wpt_i  = (const float*)d_in[5];
    const float* fc0_r  = (const float*)d_in[6];
    const float* fc0_i  = (const float*)d_in[7];
    const float* fc1_r  = (const float*)d_in[8];
    const float* fc1_i  = (const float*)d_in[9];
    const float* fc2_r  = (const float*)d_in[10];
    const float* fc2_i  = (const float*)d_in[11];
    float* outf = (float*)d_out;

    const size_t NBW = (size_t)4 * W * XYZ;
    const size_t NM  = (size_t)80 * NMODE;

    float* ws  = (float*)d_ws;
    float* eRe = ws;
    float* eIm = eRe + NM;
    float* tRe = eIm + NM;
    float* tIm = tRe + NM;
    float* xre = tIm + NM;
    float* xim = xre + NBW;

    dim3 blk(256);
    const int gP = (4 * XYZ) / 256;

    p24_fc0<<<gP, blk, 0, stream>>>(x_r, x_i, fc0_r, fc0_i, xre, xim);
    for (int l = 0; l < 4; l++) {
        p24_ixy<<<640, blk, 0, stream>>>(xre, xim, tRe, tIm);
        p24_zchain<<<256, blk, 0, stream>>>(tRe, tIm, wconv, l, eRe, eIm);
        p24_fxy<<<640, blk, 0, stream>>>(eRe, eIm, tRe, tIm);
        if (l < 3)
            p24_combine<<<gP, blk, 0, stream>>>(xre, xim, tRe, tIm,
                                                wpt_r, wpt_i, l, smooth);
    }
    p24_tail<<<gP, blk, 0, stream>>>(xre, xim, tRe, tIm, wpt_r, wpt_i, smooth,
                                     fc1_r, fc1_i, fc2_r, fc2_i, outf);
}

// Round 25
// 659.274 us; speedup vs baseline: 1.1393x; 1.0433x over previous
//
#include <hip/hip_runtime.h>
#include <hip/hip_bf16.h>
#include <math.h>

// build q25 = p24 + wave-uniform weights read via scalar loads (global, uniform
// index -> s_load) instead of LDS broadcast in tail & combine.
#define XYZ 135168   // 64*64*33
#define W 20
#define NMODE 2048   // 16*16*8
#define NREAL 3584   // 16*16*14

__device__ __forceinline__ float q25_erf(float x) {
    float s = (x < 0.f) ? -1.f : 1.f;
    float a = fabsf(x);
    float t = 1.f / fmaf(0.3275911f, a, 1.f);
    float poly = t * fmaf(t, fmaf(t, fmaf(t, fmaf(t, 1.061405429f, -1.453152027f),
                                           1.421413741f), -0.284496736f), 0.254829592f);
    float e = __expf(-a * a);
    return s * (1.f - poly * e);
}
__device__ __forceinline__ float q25_gelu(float v) {
    return 0.5f * v * (1.0f + q25_erf(v * 0.7071067811865476f));
}

__global__ __launch_bounds__(256, 4)
void q25_fc0(const float* __restrict__ xr_in, const float* __restrict__ xi_in,
             const float* __restrict__ fr, const float* __restrict__ fi,
             float* __restrict__ xre, float* __restrict__ xim) {
    int idx = blockIdx.x * blockDim.x + threadIdx.x;
    if (idx >= 4 * XYZ) return;
    int b = idx / XYZ, p = idx % XYZ;
    float ar[3], ai[3];
#pragma unroll
    for (int i = 0; i < 3; i++) {
        ar[i] = xr_in[(size_t)(b * 3 + i) * XYZ + p];
        ai[i] = xi_in[(size_t)(b * 3 + i) * XYZ + p];
    }
#pragma unroll
    for (int o = 0; o < W; o++) {
        float rr = 0.f, ii = 0.f;
#pragma unroll
        for (int i = 0; i < 3; i++) {
            float wr = fr[i * W + o], wi = fi[i * W + o];
            rr += ar[i] * wr - ai[i] * wi;
            ii += ar[i] * wi + ai[i] * wr;
        }
        xre[(size_t)(b * W + o) * XYZ + p] = rr;
        xim[(size_t)(b * W + o) * XYZ + p] = ii;
    }
}

__global__ __launch_bounds__(256, 4)
void q25_ixy(const float* __restrict__ xre, const float* __restrict__ xim,
             float* __restrict__ aRe, float* __restrict__ aIm) {
    __shared__ float s0r[256], s0i[256], s1r[256], s1i[256];
    __shared__ float twc[16], tws[16];
    int bc = blockIdx.x >> 3;
    int kz = blockIdx.x & 7;
    int t = threadIdx.x;
    int hi = t >> 4, lo = t & 15;
    if (t < 16) {
        float s, c;
        sincosf((float)t * 0.39269908169872414f, &s, &c);
        twc[t] = c; tws[t] = s;
    }
    {
        int row = (hi < 8) ? hi : hi + 48;
        int col = (lo < 8) ? lo : lo + 48;
        int off = (row * 64 + col) * 33 + kz;
        s0r[t] = xre[(size_t)bc * XYZ + off];
        s0i[t] = xim[(size_t)bc * XYZ + off];
    }
    __syncthreads();
    {
        int nx = hi, ky = lo;
        float accr = 0.f, acci = 0.f;
        for (int kx = 0; kx < 16; kx++) {
            float vr = s0r[kx * 16 + ky], vi = s0i[kx * 16 + ky];
            int m = (kx * nx) & 15;
            float c = twc[m], s = tws[m];
            accr += vr * c - vi * s;
            acci += vr * s + vi * c;
        }
        s1r[t] = accr * 0.0625f;
        s1i[t] = acci * 0.0625f;
    }
    __syncthreads();
    {
        int nx = hi, ny = lo;
        float accr = 0.f, acci = 0.f;
        for (int ky = 0; ky < 16; ky++) {
            float vr = s1r[nx * 16 + ky], vi = s1i[nx * 16 + ky];
            int m = (ky * ny) & 15;
            float c = twc[m], s = tws[m];
            accr += vr * c - vi * s;
            acci += vr * s + vi * c;
        }
        size_t o = (size_t)bc * 2048 + (size_t)t * 8 + kz;
        aRe[o] = accr * 0.0625f;
        aIm[o] = acci * 0.0625f;
    }
}

__global__ __launch_bounds__(256, 4)
void q25_zchain(const float* __restrict__ aRe, const float* __restrict__ aIm,
                const float* __restrict__ wconv, int l,
                float* __restrict__ tRe, float* __restrict__ tIm) {
    __shared__ float sar[640], sai[640];
    __shared__ float sr1[1120], sr2[1120];
    __shared__ float twc[14], tws[14];
    int b = blockIdx.x >> 6;
    int q0 = (blockIdx.x & 63) * 4;
    int tid = threadIdx.x;
    if (tid < 14) {
        float s, c;
        sincosf((float)tid * 0.4487989505128276f, &s, &c);
        twc[tid] = c; tws[tid] = s;
    }
    for (int t = tid; t < 640; t += 256) {
        int c = t >> 5;
        int dq = (t >> 3) & 3;
        int k = t & 7;
        size_t g = (size_t)(b * 20 + c) * 2048 + (size_t)(q0 + dq) * 8 + k;
        sar[t] = aRe[g];
        sai[t] = aIm[g];
    }
    __syncthreads();
    for (int t = tid; t < 1120; t += 256) {
        int c = t / 56;
        int rem = t % 56;
        int dq = rem / 14, nz = rem % 14;
        int base = c * 32 + dq * 8;
        float acc = sar[base];
        float re7 = sar[base + 7];
        acc += (nz & 1) ? -re7 : re7;
        for (int k = 1; k < 7; k++) {
            int m = (k * nz) % 14;
            acc += 2.f * (sar[base + k] * twc[m] - sai[base + k] * tws[m]);
        }
        sr1[t] = acc * (1.0f / 14.0f);
    }
    __syncthreads();
    {
        const float* wl = wconv + (size_t)l * W * W * NREAL;
        for (int t = tid; t < 1120; t += 256) {
            int o = t / 56;
            int rem = t % 56;
            int dq = rem / 14, nz = rem % 14;
            int p = (q0 + dq) * 14 + nz;
            float acc = 0.f;
#pragma unroll 4
            for (int i = 0; i < W; i++)
                acc += sr1[i * 56 + rem] * wl[(size_t)(i * W + o) * NREAL + p];
            sr2[t] = acc;
        }
    }
    __syncthreads();
    for (int t = tid; t < 640; t += 256) {
        int c = t >> 5;
        int dq = (t >> 3) & 3;
        int k = t & 7;
        int base = c * 56 + dq * 14;
        float accr = 0.f, acci = 0.f;
        for (int n = 0; n < 14; n++) {
            float v = sr2[base + n];
            int m = (k * n) % 14;
            accr += v * twc[m];
            acci -= v * tws[m];
        }
        size_t g = (size_t)(b * 20 + c) * 2048 + (size_t)(q0 + dq) * 8 + k;
        tRe[g] = accr;
        tIm[g] = acci;
    }
}

__global__ __launch_bounds__(256, 4)
void q25_fxy(const float* __restrict__ c1Re, const float* __restrict__ c1Im,
             float* __restrict__ eRe, float* __restrict__ eIm) {
    __shared__ float s0r[256], s0i[256], s1r[256], s1i[256];
    __shared__ float twc[16], tws[16];
    int bc = blockIdx.x >> 3;
    int kz = blockIdx.x & 7;
    int t = threadIdx.x;
    int hi = t >> 4, lo = t & 15;
    if (t < 16) {
        float s, c;
        sincosf((float)t * 0.39269908169872414f, &s, &c);
        twc[t] = c; tws[t] = s;
    }
    {
        size_t o = (size_t)bc * 2048 + (size_t)t * 8 + kz;
        s0r[t] = c1Re[o];
        s0i[t] = c1Im[o];
    }
    __syncthreads();
    {
        int kx = hi, ny = lo;
        float accr = 0.f, acci = 0.f;
        for (int nx = 0; nx < 16; nx++) {
            float vr = s0r[nx * 16 + ny], vi = s0i[nx * 16 + ny];
            int m = (kx * nx) & 15;
            float c = twc[m], s = tws[m];
            accr += vr * c + vi * s;
            acci += vi * c - vr * s;
        }
        s1r[t] = accr;
        s1i[t] = acci;
    }
    __syncthreads();
    {
        int kx = hi, ky = lo;
        float accr = 0.f, acci = 0.f;
        for (int ny = 0; ny < 16; ny++) {
            float vr = s1r[kx * 16 + ny], vi = s1i[kx * 16 + ny];
            int m = (ky * ny) & 15;
            float c = twc[m], s = tws[m];
            accr += vr * c + vi * s;
            acci += vi * c - vr * s;
        }
        size_t o = (size_t)bc * 2048 + (size_t)t * 8 + kz;
        eRe[o] = accr;
        eIm[o] = acci;
    }
}

// combine: weights read directly from global with wave-uniform indices
// (compiler lowers to s_load via the scalar pipe -> no LDS/VALU cost).
__global__ __launch_bounds__(256, 4)
void q25_combine(float* __restrict__ xre, float* __restrict__ xim,
                 const float* __restrict__ ere, const float* __restrict__ eim,
                 const float* __restrict__ wpt_r, const float* __restrict__ wpt_i,
                 int l, const float* __restrict__ smooth) {
    const float* wr = wpt_r + l * W * W;
    const float* wi = wpt_i + l * W * W;
    int idx = blockIdx.x * blockDim.x + threadIdx.x;
    if (idx >= 4 * XYZ) return;
    int b = idx / XYZ, p = idx % XYZ;
    int gz = p % 33;
    int gxy = p / 33;
    int gy = gxy & 63;
    int gx = gxy >> 6;
    int kx = (gx < 8) ? gx : ((gx >= 56) ? gx - 48 : -1);
    int ky = (gy < 8) ? gy : ((gy >= 56) ? gy - 48 : -1);
    bool corner = (kx >= 0) && (ky >= 0) && (gz < 8);
    float sm = smooth[p];
    float ar[W], ai[W];
#pragma unroll
    for (int i = 0; i < W; i++) {
        ar[i] = xre[(size_t)(b * W + i) * XYZ + p];
        ai[i] = xim[(size_t)(b * W + i) * XYZ + p];
    }
    int ebase = corner ? (b * W * NMODE + (kx * 16 + ky) * 8 + gz) : 0;
    for (int o = 0; o < W; o++) {
        float rr = 0.f, ii = 0.f;
#pragma unroll
        for (int i = 0; i < W; i++) {
            float wwr = wr[i * W + o], wwi = wi[i * W + o];   // uniform -> s_load
            rr += ar[i] * wwr - ai[i] * wwi;
            ii += ar[i] * wwi + ai[i] * wwr;
        }
        if (corner) {
            rr += ere[ebase + o * NMODE];
            ii += eim[ebase + o * NMODE];
        }
        rr *= sm;
        ii *= sm;
        rr = q25_gelu(rr);
        ii = q25_gelu(ii);
        xre[(size_t)(b * W + o) * XYZ + p] = rr;
        xim[(size_t)(b * W + o) * XYZ + p] = ii;
    }
}

// TAIL (minwaves 2): fused combine l=3 (no gelu) + fc1 -> cgelu -> fc2.
// fc1 & combine weights via uniform global reads (s_load); only the transposed
// 3x128 fc2 block stays in LDS.
__global__ __launch_bounds__(256, 2)
void q25_tail(const float* __restrict__ xre, const float* __restrict__ xim,
              const float* __restrict__ ere, const float* __restrict__ eim,
              const float* __restrict__ wpt_r, const float* __restrict__ wpt_i,
              const float* __restrict__ smooth,
              const float* __restrict__ f1r, const float* __restrict__ f1i,
              const float* __restrict__ f2r, const float* __restrict__ f2i,
              float* __restrict__ outf) {
    __shared__ __align__(16) float w2r[3 * 128], w2i[3 * 128];
    for (int i = threadIdx.x; i < 3 * 128; i += blockDim.x) {
        int j = i & 127, o = i >> 7;
        w2r[o * 128 + j] = f2r[j * 3 + o];
        w2i[o * 128 + j] = f2i[j * 3 + o];
    }
    const float* pwr = wpt_r + 3 * W * W;
    const float* pwi = wpt_i + 3 * W * W;
    __syncthreads();
    int idx = blockIdx.x * blockDim.x + threadIdx.x;
    if (idx >= 4 * XYZ) return;
    int b = idx / XYZ, p = idx % XYZ;
    int gz = p % 33;
    int gxy = p / 33;
    int gy = gxy & 63;
    int gx = gxy >> 6;
    int kxc = (gx < 8) ? gx : ((gx >= 56) ? gx - 48 : -1);
    int kyc = (gy < 8) ? gy : ((gy >= 56) ? gy - 48 : -1);
    bool corner = (kxc >= 0) && (kyc >= 0) && (gz < 8);
    float sm = smooth[p];
    float rr_[W], ri_[W];
    {
        float ar[W], ai[W];
#pragma unroll
        for (int i = 0; i < W; i++) {
            ar[i] = xre[(size_t)(b * W + i) * XYZ + p];
            ai[i] = xim[(size_t)(b * W + i) * XYZ + p];
        }
        int ebase = corner ? (b * W * NMODE + (kxc * 16 + kyc) * 8 + gz) : 0;
#pragma unroll 1
        for (int o = 0; o < W; o++) {
            float rr = 0.f, ii = 0.f;
#pragma unroll
            for (int i = 0; i < W; i++) {
                float wwr = pwr[i * W + o], wwi = pwi[i * W + o];  // s_load
                rr += ar[i] * wwr - ai[i] * wwi;
                ii += ar[i] * wwi + ai[i] * wwr;
            }
            if (corner) {
                rr += ere[ebase + o * NMODE];
                ii += eim[ebase + o * NMODE];
            }
            rr_[o] = rr * sm;
            ri_[o] = ii * sm;
        }
    }
    float accr[3] = {0.f, 0.f, 0.f};
    for (int jc = 0; jc < 16; jc++) {
        int jb = jc * 8;
        float tr[8], ti[8];
#pragma unroll
        for (int jj = 0; jj < 8; jj++) { tr[jj] = 0.f; ti[jj] = 0.f; }
#pragma unroll 2
        for (int i = 0; i < W; i++) {
            // uniform global reads -> scalar loads (no LDS, no VALU)
            float4 wrA = *(const float4*)&f1r[i * 128 + jb];
            float4 wrB = *(const float4*)&f1r[i * 128 + jb + 4];
            float4 wiA = *(const float4*)&f1i[i * 128 + jb];
            float4 wiB = *(const float4*)&f1i[i * 128 + jb + 4];
            float xr_ = rr_[i], xi_ = ri_[i];
            tr[0] += xr_ * wrA.x - xi_ * wiA.x;  ti[0] += xr_ * wiA.x + xi_ * wrA.x;
            tr[1] += xr_ * wrA.y - xi_ * wiA.y;  ti[1] += xr_ * wiA.y + xi_ * wrA.y;
            tr[2] += xr_ * wrA.z - xi_ * wiA.z;  ti[2] += xr_ * wiA.z + xi_ * wrA.z;
            tr[3] += xr_ * wrA.w - xi_ * wiA.w;  ti[3] += xr_ * wiA.w + xi_ * wrA.w;
            tr[4] += xr_ * wrB.x - xi_ * wiB.x;  ti[4] += xr_ * wiB.x + xi_ * wrB.x;
            tr[5] += xr_ * wrB.y - xi_ * wiB.y;  ti[5] += xr_ * wiB.y + xi_ * wrB.y;
            tr[6] += xr_ * wrB.z - xi_ * wiB.z;  ti[6] += xr_ * wiB.z + xi_ * wrB.z;
            tr[7] += xr_ * wrB.w - xi_ * wiB.w;  ti[7] += xr_ * wiB.w + xi_ * wrB.w;
        }
#pragma unroll
        for (int jj = 0; jj < 8; jj++) {
            tr[jj] = q25_gelu(tr[jj]);
            ti[jj] = q25_gelu(ti[jj]);
        }
#pragma unroll
        for (int o = 0; o < 3; o++) {
            float4 crA = *(const float4*)&w2r[o * 128 + jb];
            float4 crB = *(const float4*)&w2r[o * 128 + jb + 4];
            float4 ciA = *(const float4*)&w2i[o * 128 + jb];
            float4 ciB = *(const float4*)&w2i[o * 128 + jb + 4];
            accr[o] += tr[0] * crA.x - ti[0] * ciA.x;
            accr[o] += tr[1] * crA.y - ti[1] * ciA.y;
            accr[o] += tr[2] * crA.z - ti[2] * ciA.z;
            accr[o] += tr[3] * crA.w - ti[3] * ciA.w;
            accr[o] += tr[4] * crB.x - ti[4] * ciB.x;
            accr[o] += tr[5] * crB.y - ti[5] * ciB.y;
            accr[o] += tr[6] * crB.z - ti[6] * ciB.z;
            accr[o] += tr[7] * crB.w - ti[7] * ciB.w;
        }
    }
#pragma unroll
    for (int o = 0; o < 3; o++) {
        size_t k = (size_t)(b * 3 + o) * XYZ + p;
        outf[k] = __bfloat162float(__float2bfloat16(accr[o]));
    }
}

extern "C" void kernel_launch(void* const* d_in, const int* in_sizes, int n_in,
                              void* d_out, int out_size, void* d_ws, size_t ws_size,
                              hipStream_t stream) {
    const float* x_r    = (const float*)d_in[0];
    const float* x_i    = (const float*)d_in[1];
    const float* smooth = (const float*)d_in[2];
    const float* wconv  = (const float*)d_in[3];
    const float* wpt_r  = (const float*)d_in[4];
    const float* wpt_i  = (const float*)d_in[5];
    const float* fc0_r  = (const float*)d_in[6];
    const float* fc0_i  = (const float*)d_in[7];
    const float* fc1_r  = (const float*)d_in[8];
    const float* fc1_i  = (const float*)d_in[9];
    const float* fc2_r  = (const float*)d_in[10];
    const float* fc2_i  = (const float*)d_in[11];
    float* outf = (float*)d_out;

    const size_t NBW = (size_t)4 * W * XYZ;
    const size_t NM  = (size_t)80 * NMODE;

    float* ws  = (float*)d_ws;
    float* eRe = ws;
    float* eIm = eRe + NM;
    float* tRe = eIm + NM;
    float* tIm = tRe + NM;
    float* xre = tIm + NM;
    float* xim = xre + NBW;

    dim3 blk(256);
    const int gP = (4 * XYZ) / 256;

    q25_fc0<<<gP, blk, 0, stream>>>(x_r, x_i, fc0_r, fc0_i, xre, xim);
    for (int l = 0; l < 4; l++) {
        q25_ixy<<<640, blk, 0, stream>>>(xre, xim, tRe, tIm);
        q25_zchain<<<256, blk, 0, stream>>>(tRe, tIm, wconv, l, eRe, eIm);
        q25_fxy<<<640, blk, 0, stream>>>(eRe, eIm, tRe, tIm);
        if (l < 3)
            q25_combine<<<gP, blk, 0, stream>>>(xre, xim, tRe, tIm,
                                                wpt_r, wpt_i, l, smooth);
    }
    q25_tail<<<gP, blk, 0, stream>>>(xre, xim, tRe, tIm, wpt_r, wpt_i, smooth,
                                     fc1_r, fc1_i, fc2_r, fc2_i, outf);
}

// Round 26
// 647.037 us; speedup vs baseline: 1.1609x; 1.0189x over previous
//
#include <hip/hip_runtime.h>
#include <hip/hip_bf16.h>
#include <math.h>

// build r26 = q25 + compact corner mirror xc[bc][kz][kxky] written by fc0 &
// combine (1.5% of threads), so ixy's gather is fully coalesced.
#define XYZ 135168   // 64*64*33
#define W 20
#define NMODE 2048   // 16*16*8
#define NREAL 3584   // 16*16*14

__device__ __forceinline__ float r26_erf(float x) {
    float s = (x < 0.f) ? -1.f : 1.f;
    float a = fabsf(x);
    float t = 1.f / fmaf(0.3275911f, a, 1.f);
    float poly = t * fmaf(t, fmaf(t, fmaf(t, fmaf(t, 1.061405429f, -1.453152027f),
                                           1.421413741f), -0.284496736f), 0.254829592f);
    float e = __expf(-a * a);
    return s * (1.f - poly * e);
}
__device__ __forceinline__ float r26_gelu(float v) {
    return 0.5f * v * (1.0f + r26_erf(v * 0.7071067811865476f));
}

// fc0: lift 3 -> 20; also mirror corner values into xc (dense, [bc][kz][kxky]).
__global__ __launch_bounds__(256, 4)
void r26_fc0(const float* __restrict__ xr_in, const float* __restrict__ xi_in,
             const float* __restrict__ fr, const float* __restrict__ fi,
             float* __restrict__ xre, float* __restrict__ xim,
             float* __restrict__ xcRe, float* __restrict__ xcIm) {
    int idx = blockIdx.x * blockDim.x + threadIdx.x;
    if (idx >= 4 * XYZ) return;
    int b = idx / XYZ, p = idx % XYZ;
    int gz = p % 33;
    int gxy = p / 33;
    int gy = gxy & 63;
    int gx = gxy >> 6;
    int kx = (gx < 8) ? gx : ((gx >= 56) ? gx - 48 : -1);
    int ky = (gy < 8) ? gy : ((gy >= 56) ? gy - 48 : -1);
    bool corner = (kx >= 0) && (ky >= 0) && (gz < 8);
    int cidx = corner ? (gz * 256 + kx * 16 + ky) : 0;
    float ar[3], ai[3];
#pragma unroll
    for (int i = 0; i < 3; i++) {
        ar[i] = xr_in[(size_t)(b * 3 + i) * XYZ + p];
        ai[i] = xi_in[(size_t)(b * 3 + i) * XYZ + p];
    }
#pragma unroll
    for (int o = 0; o < W; o++) {
        float rr = 0.f, ii = 0.f;
#pragma unroll
        for (int i = 0; i < 3; i++) {
            float wr = fr[i * W + o], wi = fi[i * W + o];
            rr += ar[i] * wr - ai[i] * wi;
            ii += ar[i] * wi + ai[i] * wr;
        }
        xre[(size_t)(b * W + o) * XYZ + p] = rr;
        xim[(size_t)(b * W + o) * XYZ + p] = ii;
        if (corner) {
            xcRe[(size_t)(b * W + o) * 2048 + cidx] = rr;
            xcIm[(size_t)(b * W + o) * 2048 + cidx] = ii;
        }
    }
}

// ixy: coalesced read from xc[bc][kz][kxky]; rest identical.
__global__ __launch_bounds__(256, 4)
void r26_ixy(const float* __restrict__ xcRe, const float* __restrict__ xcIm,
             float* __restrict__ aRe, float* __restrict__ aIm) {
    __shared__ float s0r[256], s0i[256], s1r[256], s1i[256];
    __shared__ float twc[16], tws[16];
    int bc = blockIdx.x >> 3;
    int kz = blockIdx.x & 7;
    int t = threadIdx.x;
    int hi = t >> 4, lo = t & 15;
    if (t < 16) {
        float s, c;
        sincosf((float)t * 0.39269908169872414f, &s, &c);
        twc[t] = c; tws[t] = s;
    }
    {
        size_t g = (size_t)bc * 2048 + (size_t)kz * 256 + t;
        s0r[t] = xcRe[g];           // s0[kx*16+ky], fully coalesced
        s0i[t] = xcIm[g];
    }
    __syncthreads();
    {
        int nx = hi, ky = lo;
        float accr = 0.f, acci = 0.f;
        for (int kx = 0; kx < 16; kx++) {
            float vr = s0r[kx * 16 + ky], vi = s0i[kx * 16 + ky];
            int m = (kx * nx) & 15;
            float c = twc[m], s = tws[m];
            accr += vr * c - vi * s;
            acci += vr * s + vi * c;
        }
        s1r[t] = accr * 0.0625f;
        s1i[t] = acci * 0.0625f;
    }
    __syncthreads();
    {
        int nx = hi, ny = lo;
        float accr = 0.f, acci = 0.f;
        for (int ky = 0; ky < 16; ky++) {
            float vr = s1r[nx * 16 + ky], vi = s1i[nx * 16 + ky];
            int m = (ky * ny) & 15;
            float c = twc[m], s = tws[m];
            accr += vr * c - vi * s;
            acci += vr * s + vi * c;
        }
        size_t o = (size_t)bc * 2048 + (size_t)t * 8 + kz;
        aRe[o] = accr * 0.0625f;
        aIm[o] = acci * 0.0625f;
    }
}

__global__ __launch_bounds__(256, 4)
void r26_zchain(const float* __restrict__ aRe, const float* __restrict__ aIm,
                const float* __restrict__ wconv, int l,
                float* __restrict__ tRe, float* __restrict__ tIm) {
    __shared__ float sar[640], sai[640];
    __shared__ float sr1[1120], sr2[1120];
    __shared__ float twc[14], tws[14];
    int b = blockIdx.x >> 6;
    int q0 = (blockIdx.x & 63) * 4;
    int tid = threadIdx.x;
    if (tid < 14) {
        float s, c;
        sincosf((float)tid * 0.4487989505128276f, &s, &c);
        twc[tid] = c; tws[tid] = s;
    }
    for (int t = tid; t < 640; t += 256) {
        int c = t >> 5;
        int dq = (t >> 3) & 3;
        int k = t & 7;
        size_t g = (size_t)(b * 20 + c) * 2048 + (size_t)(q0 + dq) * 8 + k;
        sar[t] = aRe[g];
        sai[t] = aIm[g];
    }
    __syncthreads();
    for (int t = tid; t < 1120; t += 256) {
        int c = t / 56;
        int rem = t % 56;
        int dq = rem / 14, nz = rem % 14;
        int base = c * 32 + dq * 8;
        float acc = sar[base];
        float re7 = sar[base + 7];
        acc += (nz & 1) ? -re7 : re7;
        for (int k = 1; k < 7; k++) {
            int m = (k * nz) % 14;
            acc += 2.f * (sar[base + k] * twc[m] - sai[base + k] * tws[m]);
        }
        sr1[t] = acc * (1.0f / 14.0f);
    }
    __syncthreads();
    {
        const float* wl = wconv + (size_t)l * W * W * NREAL;
        for (int t = tid; t < 1120; t += 256) {
            int o = t / 56;
            int rem = t % 56;
            int dq = rem / 14, nz = rem % 14;
            int p = (q0 + dq) * 14 + nz;
            float acc = 0.f;
#pragma unroll 4
            for (int i = 0; i < W; i++)
                acc += sr1[i * 56 + rem] * wl[(size_t)(i * W + o) * NREAL + p];
            sr2[t] = acc;
        }
    }
    __syncthreads();
    for (int t = tid; t < 640; t += 256) {
        int c = t >> 5;
        int dq = (t >> 3) & 3;
        int k = t & 7;
        int base = c * 56 + dq * 14;
        float accr = 0.f, acci = 0.f;
        for (int n = 0; n < 14; n++) {
            float v = sr2[base + n];
            int m = (k * n) % 14;
            accr += v * twc[m];
            acci -= v * tws[m];
        }
        size_t g = (size_t)(b * 20 + c) * 2048 + (size_t)(q0 + dq) * 8 + k;
        tRe[g] = accr;
        tIm[g] = acci;
    }
}

__global__ __launch_bounds__(256, 4)
void r26_fxy(const float* __restrict__ c1Re, const float* __restrict__ c1Im,
             float* __restrict__ eRe, float* __restrict__ eIm) {
    __shared__ float s0r[256], s0i[256], s1r[256], s1i[256];
    __shared__ float twc[16], tws[16];
    int bc = blockIdx.x >> 3;
    int kz = blockIdx.x & 7;
    int t = threadIdx.x;
    int hi = t >> 4, lo = t & 15;
    if (t < 16) {
        float s, c;
        sincosf((float)t * 0.39269908169872414f, &s, &c);
        twc[t] = c; tws[t] = s;
    }
    {
        size_t o = (size_t)bc * 2048 + (size_t)t * 8 + kz;
        s0r[t] = c1Re[o];
        s0i[t] = c1Im[o];
    }
    __syncthreads();
    {
        int kx = hi, ny = lo;
        float accr = 0.f, acci = 0.f;
        for (int nx = 0; nx < 16; nx++) {
            float vr = s0r[nx * 16 + ny], vi = s0i[nx * 16 + ny];
            int m = (kx * nx) & 15;
            float c = twc[m], s = tws[m];
            accr += vr * c + vi * s;
            acci += vi * c - vr * s;
        }
        s1r[t] = accr;
        s1i[t] = acci;
    }
    __syncthreads();
    {
        int kx = hi, ky = lo;
        float accr = 0.f, acci = 0.f;
        for (int ny = 0; ny < 16; ny++) {
            float vr = s1r[kx * 16 + ny], vi = s1i[kx * 16 + ny];
            int m = (ky * ny) & 15;
            float c = twc[m], s = tws[m];
            accr += vr * c + vi * s;
            acci += vi * c - vr * s;
        }
        size_t o = (size_t)bc * 2048 + (size_t)t * 8 + kz;
        eRe[o] = accr;
        eIm[o] = acci;
    }
}

// combine: s_load weights; ALSO mirrors corner results into xc for next ixy.
__global__ __launch_bounds__(256, 4)
void r26_combine(float* __restrict__ xre, float* __restrict__ xim,
                 const float* __restrict__ ere, const float* __restrict__ eim,
                 const float* __restrict__ wpt_r, const float* __restrict__ wpt_i,
                 int l, const float* __restrict__ smooth,
                 float* __restrict__ xcRe, float* __restrict__ xcIm) {
    const float* wr = wpt_r + l * W * W;
    const float* wi = wpt_i + l * W * W;
    int idx = blockIdx.x * blockDim.x + threadIdx.x;
    if (idx >= 4 * XYZ) return;
    int b = idx / XYZ, p = idx % XYZ;
    int gz = p % 33;
    int gxy = p / 33;
    int gy = gxy & 63;
    int gx = gxy >> 6;
    int kx = (gx < 8) ? gx : ((gx >= 56) ? gx - 48 : -1);
    int ky = (gy < 8) ? gy : ((gy >= 56) ? gy - 48 : -1);
    bool corner = (kx >= 0) && (ky >= 0) && (gz < 8);
    int cidx = corner ? (gz * 256 + kx * 16 + ky) : 0;
    float sm = smooth[p];
    float ar[W], ai[W];
#pragma unroll
    for (int i = 0; i < W; i++) {
        ar[i] = xre[(size_t)(b * W + i) * XYZ + p];
        ai[i] = xim[(size_t)(b * W + i) * XYZ + p];
    }
    int ebase = corner ? (b * W * NMODE + (kx * 16 + ky) * 8 + gz) : 0;
    for (int o = 0; o < W; o++) {
        float rr = 0.f, ii = 0.f;
#pragma unroll
        for (int i = 0; i < W; i++) {
            float wwr = wr[i * W + o], wwi = wi[i * W + o];
            rr += ar[i] * wwr - ai[i] * wwi;
            ii += ar[i] * wwi + ai[i] * wwr;
        }
        if (corner) {
            rr += ere[ebase + o * NMODE];
            ii += eim[ebase + o * NMODE];
        }
        rr *= sm;
        ii *= sm;
        rr = r26_gelu(rr);
        ii = r26_gelu(ii);
        xre[(size_t)(b * W + o) * XYZ + p] = rr;
        xim[(size_t)(b * W + o) * XYZ + p] = ii;
        if (corner) {
            xcRe[(size_t)(b * W + o) * 2048 + cidx] = rr;
            xcIm[(size_t)(b * W + o) * 2048 + cidx] = ii;
        }
    }
}

// TAIL (minwaves 2): fused combine l=3 (no gelu) + fc1 -> cgelu -> fc2.
__global__ __launch_bounds__(256, 2)
void r26_tail(const float* __restrict__ xre, const float* __restrict__ xim,
              const float* __restrict__ ere, const float* __restrict__ eim,
              const float* __restrict__ wpt_r, const float* __restrict__ wpt_i,
              const float* __restrict__ smooth,
              const float* __restrict__ f1r, const float* __restrict__ f1i,
              const float* __restrict__ f2r, const float* __restrict__ f2i,
              float* __restrict__ outf) {
    __shared__ __align__(16) float w2r[3 * 128], w2i[3 * 128];
    for (int i = threadIdx.x; i < 3 * 128; i += blockDim.x) {
        int j = i & 127, o = i >> 7;
        w2r[o * 128 + j] = f2r[j * 3 + o];
        w2i[o * 128 + j] = f2i[j * 3 + o];
    }
    const float* pwr = wpt_r + 3 * W * W;
    const float* pwi = wpt_i + 3 * W * W;
    __syncthreads();
    int idx = blockIdx.x * blockDim.x + threadIdx.x;
    if (idx >= 4 * XYZ) return;
    int b = idx / XYZ, p = idx % XYZ;
    int gz = p % 33;
    int gxy = p / 33;
    int gy = gxy & 63;
    int gx = gxy >> 6;
    int kxc = (gx < 8) ? gx : ((gx >= 56) ? gx - 48 : -1);
    int kyc = (gy < 8) ? gy : ((gy >= 56) ? gy - 48 : -1);
    bool corner = (kxc >= 0) && (kyc >= 0) && (gz < 8);
    float sm = smooth[p];
    float rr_[W], ri_[W];
    {
        float ar[W], ai[W];
#pragma unroll
        for (int i = 0; i < W; i++) {
            ar[i] = xre[(size_t)(b * W + i) * XYZ + p];
            ai[i] = xim[(size_t)(b * W + i) * XYZ + p];
        }
        int ebase = corner ? (b * W * NMODE + (kxc * 16 + kyc) * 8 + gz) : 0;
#pragma unroll 1
        for (int o = 0; o < W; o++) {
            float rr = 0.f, ii = 0.f;
#pragma unroll
            for (int i = 0; i < W; i++) {
                float wwr = pwr[i * W + o], wwi = pwi[i * W + o];
                rr += ar[i] * wwr - ai[i] * wwi;
                ii += ar[i] * wwi + ai[i] * wwr;
            }
            if (corner) {
                rr += ere[ebase + o * NMODE];
                ii += eim[ebase + o * NMODE];
            }
            rr_[o] = rr * sm;
            ri_[o] = ii * sm;
        }
    }
    float accr[3] = {0.f, 0.f, 0.f};
    for (int jc = 0; jc < 16; jc++) {
        int jb = jc * 8;
        float tr[8], ti[8];
#pragma unroll
        for (int jj = 0; jj < 8; jj++) { tr[jj] = 0.f; ti[jj] = 0.f; }
#pragma unroll 2
        for (int i = 0; i < W; i++) {
            float4 wrA = *(const float4*)&f1r[i * 128 + jb];
            float4 wrB = *(const float4*)&f1r[i * 128 + jb + 4];
            float4 wiA = *(const float4*)&f1i[i * 128 + jb];
            float4 wiB = *(const float4*)&f1i[i * 128 + jb + 4];
            float xr_ = rr_[i], xi_ = ri_[i];
            tr[0] += xr_ * wrA.x - xi_ * wiA.x;  ti[0] += xr_ * wiA.x + xi_ * wrA.x;
            tr[1] += xr_ * wrA.y - xi_ * wiA.y;  ti[1] += xr_ * wiA.y + xi_ * wrA.y;
            tr[2] += xr_ * wrA.z - xi_ * wiA.z;  ti[2] += xr_ * wiA.z + xi_ * wrA.z;
            tr[3] += xr_ * wrA.w - xi_ * wiA.w;  ti[3] += xr_ * wiA.w + xi_ * wrA.w;
            tr[4] += xr_ * wrB.x - xi_ * wiB.x;  ti[4] += xr_ * wiB.x + xi_ * wrB.x;
            tr[5] += xr_ * wrB.y - xi_ * wiB.y;  ti[5] += xr_ * wiB.y + xi_ * wrB.y;
            tr[6] += xr_ * wrB.z - xi_ * wiB.z;  ti[6] += xr_ * wiB.z + xi_ * wrB.z;
            tr[7] += xr_ * wrB.w - xi_ * wiB.w;  ti[7] += xr_ * wiB.w + xi_ * wrB.w;
        }
#pragma unroll
        for (int jj = 0; jj < 8; jj++) {
            tr[jj] = r26_gelu(tr[jj]);
            ti[jj] = r26_gelu(ti[jj]);
        }
#pragma unroll
        for (int o = 0; o < 3; o++) {
            float4 crA = *(const float4*)&w2r[o * 128 + jb];
            float4 crB = *(const float4*)&w2r[o * 128 + jb + 4];
            float4 ciA = *(const float4*)&w2i[o * 128 + jb];
            float4 ciB = *(const float4*)&w2i[o * 128 + jb + 4];
            accr[o] += tr[0] * crA.x - ti[0] * ciA.x;
            accr[o] += tr[1] * crA.y - ti[1] * ciA.y;
            accr[o] += tr[2] * crA.z - ti[2] * ciA.z;
            accr[o] += tr[3] * crA.w - ti[3] * ciA.w;
            accr[o] += tr[4] * crB.x - ti[4] * ciB.x;
            accr[o] += tr[5] * crB.y - ti[5] * ciB.y;
            accr[o] += tr[6] * crB.z - ti[6] * ciB.z;
            accr[o] += tr[7] * crB.w - ti[7] * ciB.w;
        }
    }
#pragma unroll
    for (int o = 0; o < 3; o++) {
        size_t k = (size_t)(b * 3 + o) * XYZ + p;
        outf[k] = __bfloat162float(__float2bfloat16(accr[o]));
    }
}

extern "C" void kernel_launch(void* const* d_in, const int* in_sizes, int n_in,
                              void* d_out, int out_size, void* d_ws, size_t ws_size,
                              hipStream_t stream) {
    const float* x_r    = (const float*)d_in[0];
    const float* x_i    = (const float*)d_in[1];
    const float* smooth = (const float*)d_in[2];
    const float* wconv  = (const float*)d_in[3];
    const float* wpt_r  = (const float*)d_in[4];
    const float* wpt_i  = (const float*)d_in[5];
    const float* fc0_r  = (const float*)d_in[6];
    const float* fc0_i  = (const float*)d_in[7];
    const float* fc1_r  = (const float*)d_in[8];
    const float* fc1_i  = (const float*)d_in[9];
    const float* fc2_r  = (const float*)d_in[10];
    const float* fc2_i  = (const float*)d_in[11];
    float* outf = (float*)d_out;

    const size_t NBW = (size_t)4 * W * XYZ;
    const size_t NM  = (size_t)80 * NMODE;

    float* ws   = (float*)d_ws;
    float* eRe  = ws;
    float* eIm  = eRe + NM;
    float* tRe  = eIm + NM;
    float* tIm  = tRe + NM;
    float* xcRe = tIm + NM;
    float* xcIm = xcRe + NM;
    float* xre  = xcIm + NM;
    float* xim  = xre + NBW;

    dim3 blk(256);
    const int gP = (4 * XYZ) / 256;

    r26_fc0<<<gP, blk, 0, stream>>>(x_r, x_i, fc0_r, fc0_i, xre, xim, xcRe, xcIm);
    for (int l = 0; l < 4; l++) {
        r26_ixy<<<640, blk, 0, stream>>>(xcRe, xcIm, tRe, tIm);
        r26_zchain<<<256, blk, 0, stream>>>(tRe, tIm, wconv, l, eRe, eIm);
        r26_fxy<<<640, blk, 0, stream>>>(eRe, eIm, tRe, tIm);
        if (l < 3)
            r26_combine<<<gP, blk, 0, stream>>>(xre, xim, tRe, tIm,
                                                wpt_r, wpt_i, l, smooth,
                                                xcRe, xcIm);
    }
    r26_tail<<<gP, blk, 0, stream>>>(xre, xim, tRe, tIm, wpt_r, wpt_i, smooth,
                                     fc1_r, fc1_i, fc2_r, fc2_i, outf);
}